// Round 13
// baseline (80.425 us; speedup 1.0000x reference)
//
#include <hip/hip_runtime.h>
#include <math.h>

#define D_DIM 1280
#define ODIM  510

typedef short bf16x8 __attribute__((ext_vector_type(8)));   // 8 bf16 = 4 VGPRs
typedef float f32x4  __attribute__((ext_vector_type(4)));
typedef unsigned uint2n __attribute__((ext_vector_type(2)));

// pack two fp32 -> packed bf16 pair (round-half-up)
__device__ __forceinline__ unsigned pkbf(float a, float b) {
  unsigned ua = __float_as_uint(a), ub = __float_as_uint(b);
  return ((ua + 0x8000u) >> 16) | ((ub + 0x8000u) & 0xffff0000u);
}

// Single fused kernel. out[oi][oj][k] = b[k] + sum_d X[oi+1,d]*X[oj+1,d]*W[d][k],
// symmetric in (oi,oj) (antisym diff-term cancels). Upper triangle of the 32x32
// grid of 16x16 tiles (528 blocks). 4 waves split K into quarters; each wave
// stages ITS OWN quarter (2 chunks of 160) from clean fp32 X into private LDS in
// MFMA fragment order -> no __syncthreads in the K path, coalesced global reads,
// no workspace round-trip.
__global__ __launch_bounds__(256, 2) void pcmd_fused(
    const float* __restrict__ X,   // [512][1280]
    const float* __restrict__ W,   // [2560][2] (first 1280 rows = Wp)
    const float* __restrict__ b,   // [2]
    float* __restrict__ out)       // [510][510][2]
{
  __shared__ float sW[2 * D_DIM];                 // 10,240 B: (w0,w1) per d
  __shared__ unsigned short sF[4][3][5][64][8];   // 61,440 B: [wave][plane][kstep][granule][8]
  __shared__ float sR[4][2][16][17];              // 8,704 B: cross-wave reduce

  // linear block id -> (bi, bj), bi <= bj
  const int t = (int)blockIdx.x;   // 0..527
  int bi = (int)((65.0 - sqrt(4225.0 - 8.0 * (double)t)) * 0.5);
  {
    int s0 = bi * 32 - (bi * (bi - 1)) / 2;
    if (t < s0) { --bi; }
    int s1 = (bi + 1) * 32 - ((bi + 1) * bi) / 2;
    if (t >= s1) { ++bi; }
  }
  const int start = bi * 32 - (bi * (bi - 1)) / 2;
  const int bj = bi + (t - start);

  const int tid  = threadIdx.x;
  const int lane = tid & 63;
  const int wv   = tid >> 6;       // K-quarter owner
  const int iT = bi * 16, jT = bj * 16;

  // stage W once (coalesced float4), single barrier
  for (int i = tid; i < 640; i += 256)
    *(float4*)(sW + i * 4) = *(const float4*)(W + i * 4);
  __syncthreads();

  f32x4 acc0 = {0.f, 0.f, 0.f, 0.f};
  f32x4 acc1 = {0.f, 0.f, 0.f, 0.f};

  #pragma unroll 1
  for (int ch = 0; ch < 2; ++ch) {
    const int kb = wv * 320 + ch * 160;    // this wave-chunk's k-base

    // ---- B-side: rows jT..jT+15, 160 k's = 640 float4, 10 tasks/lane ----
    float4 xb[10];
    #pragma unroll
    for (int tk = 0; tk < 10; ++tk) {
      const int g = tk * 64 + lane;
      const int lr = g / 40, c4 = g - lr * 40;
      const int prow = jT + lr;            // out row; X row = prow+1
      if (prow <= 509) xb[tk] = *(const float4*)(X + (size_t)(prow + 1) * D_DIM + kb + c4 * 4);
      else             xb[tk] = make_float4(0.f, 0.f, 0.f, 0.f);
    }
    #pragma unroll
    for (int tk = 0; tk < 10; ++tk) {
      const int g = tk * 64 + lane;
      const int lr = g / 40, c4 = g - lr * 40;
      const int s = c4 >> 3, quad = (c4 >> 1) & 3, half = c4 & 1;
      const int rot = (lr + 5 * s) & 15;   // bank-spread rotation
      uint2n u;
      u.x = pkbf(xb[tk].x, xb[tk].y);
      u.y = pkbf(xb[tk].z, xb[tk].w);
      *(uint2n*)&sF[wv][0][s][quad * 16 + rot][half * 4] = u;
    }

    // ---- A-side: rows iT..iT+15, packs X*w0 / X*w1 ----
    float4 xa[10], wqa[10], wqb[10];
    #pragma unroll
    for (int tk = 0; tk < 10; ++tk) {
      const int g = tk * 64 + lane;
      const int lr = g / 40, c4 = g - lr * 40;
      const int prow = iT + lr;
      if (prow <= 509) xa[tk] = *(const float4*)(X + (size_t)(prow + 1) * D_DIM + kb + c4 * 4);
      else             xa[tk] = make_float4(0.f, 0.f, 0.f, 0.f);
      const float* wp = sW + 2 * (kb + c4 * 4);      // 32B-aligned
      wqa[tk] = *(const float4*)wp;                  // w0[k],w1[k],w0[k+1],w1[k+1]
      wqb[tk] = *(const float4*)(wp + 4);            // k+2, k+3
    }
    #pragma unroll
    for (int tk = 0; tk < 10; ++tk) {
      const int g = tk * 64 + lane;
      const int lr = g / 40, c4 = g - lr * 40;
      const int s = c4 >> 3, quad = (c4 >> 1) & 3, half = c4 & 1;
      const int rot = (lr + 5 * s) & 15;
      uint2n u0, u1;
      u0.x = pkbf(xa[tk].x * wqa[tk].x, xa[tk].y * wqa[tk].z);
      u0.y = pkbf(xa[tk].z * wqb[tk].x, xa[tk].w * wqb[tk].z);
      u1.x = pkbf(xa[tk].x * wqa[tk].y, xa[tk].y * wqa[tk].w);
      u1.y = pkbf(xa[tk].z * wqb[tk].y, xa[tk].w * wqb[tk].w);
      *(uint2n*)&sF[wv][1][s][quad * 16 + rot][half * 4] = u0;
      *(uint2n*)&sF[wv][2][s][quad * 16 + rot][half * 4] = u1;
    }

    // ---- MFMA over this chunk's 5 k-steps (same-wave LDS dep: no barrier) ----
    #pragma unroll
    for (int s = 0; s < 5; ++s) {
      const int gq = (lane & 48) + (((lane & 15) + 5 * s) & 15);  // quad*16 + rot(m)
      bf16x8 fb  = *(const bf16x8*)&sF[wv][0][s][gq][0];
      bf16x8 fa0 = *(const bf16x8*)&sF[wv][1][s][gq][0];
      bf16x8 fa1 = *(const bf16x8*)&sF[wv][2][s][gq][0];
      acc0 = __builtin_amdgcn_mfma_f32_16x16x32_bf16(fa0, fb, acc0, 0, 0, 0);
      acc1 = __builtin_amdgcn_mfma_f32_16x16x32_bf16(fa1, fb, acc1, 0, 0, 0);
    }
  }

  // ---- cross-wave K reduce + symmetric store ----
  // C/D layout: col = lane&15 (j), row = quad*4 + reg (i)  [verified m89/m91]
  const int m = lane & 15, quad = lane >> 4;
  #pragma unroll
  for (int r = 0; r < 4; ++r) {
    sR[wv][0][quad * 4 + r][m] = acc0[r];
    sR[wv][1][quad * 4 + r][m] = acc1[r];
  }
  __syncthreads();

  const float b0 = b[0], b1 = b[1];
  const int il = tid >> 4, jl = tid & 15;

  {
    const int oi = iT + il, oj = jT + jl;
    if (oi < ODIM && oj < ODIM) {
      float2 v;
      v.x = sR[0][0][il][jl] + sR[1][0][il][jl] + sR[2][0][il][jl] + sR[3][0][il][jl] + b0;
      v.y = sR[0][1][il][jl] + sR[1][1][il][jl] + sR[2][1][il][jl] + sR[3][1][il][jl] + b1;
      *(float2*)(out + ((size_t)oi * ODIM + oj) * 2) = v;
    }
  }
  if (bi != bj) {   // transposed tile; LDS stride 17 -> conflict-free
    const int oi = jT + il, oj = iT + jl;
    if (oi < ODIM && oj < ODIM) {
      float2 v;
      v.x = sR[0][0][jl][il] + sR[1][0][jl][il] + sR[2][0][jl][il] + sR[3][0][jl][il] + b0;
      v.y = sR[0][1][jl][il] + sR[1][1][jl][il] + sR[2][1][jl][il] + sR[3][1][jl][il] + b1;
      *(float2*)(out + ((size_t)oi * ODIM + oj) * 2) = v;
    }
  }
}

extern "C" void kernel_launch(void* const* d_in, const int* in_sizes, int n_in,
                              void* d_out, int out_size, void* d_ws, size_t ws_size,
                              hipStream_t stream) {
  const float* X = (const float*)d_in[0];
  const float* W = (const float*)d_in[1];
  const float* b = (const float*)d_in[2];
  float* out = (float*)d_out;
  (void)in_sizes; (void)n_in; (void)out_size; (void)d_ws; (void)ws_size;

  hipLaunchKernelGGL(pcmd_fused, dim3(528), dim3(256), 0, stream, X, W, b, out);
}

// Round 14
// 71.282 us; speedup vs baseline: 1.1283x; 1.1283x over previous
//
#include <hip/hip_runtime.h>
#include <math.h>

#define D_DIM 1280
#define ODIM  510
#define KSTEPS 40           // 1280 / 32
#define QK    320           // d's per K-quarter

typedef short bf16x8 __attribute__((ext_vector_type(8)));   // 8 bf16 = 4 VGPRs
typedef float f32x4  __attribute__((ext_vector_type(4)));
typedef unsigned uint4n __attribute__((ext_vector_type(4)));

// pack two fp32 -> packed bf16 pair (round-half-up)
__device__ __forceinline__ unsigned pkbf(float a, float b) {
  unsigned ua = __float_as_uint(a), ub = __float_as_uint(b);
  return ((ua + 0x8000u) >> 16) | ((ub + 0x8000u) & 0xffff0000u);
}

// Prep (R12 structure): fragment-ordered bf16 planes via LDS transpose; both
// global sides coalesced. ONE CHANGE vs R12: phase-2 stores are NON-TEMPORAL so
// plane lines do NOT sit dirty in the producer XCD's L2 — consumer gemm misses
// become clean L3 service instead of cross-XCD dirty snoops.
__global__ __launch_bounds__(256, 1) void pcmd_prep(
    const float* __restrict__ X,        // [512][1280]
    const float* __restrict__ W,        // [2560][2] (first 1280 rows = Wp)
    unsigned short* __restrict__ Xbf,   // fragment-ordered planes
    unsigned short* __restrict__ A0,
    unsigned short* __restrict__ A1)
{
  __shared__ unsigned short sG[3][10][64][8];   // 30 KB

  const int R   = (int)blockIdx.x >> 2;   // row-block 0..31
  const int q   = (int)blockIdx.x & 3;    // K-quarter 0..3
  const int tid = threadIdx.x;

  // ---- phase 1: 640 tasks = 16 rows x 40 granules ----
  for (int task = tid; task < 640; task += 256) {
    const int lr = task / 40;             // local row 0..15
    const int gc = task - lr * 40;        // granule-in-quarter 0..39
    const int s = gc >> 2, quad = gc & 3;
    const int prow = R * 16 + lr;         // plane row
    uint4 vx = {0,0,0,0}, v0 = {0,0,0,0}, v1 = {0,0,0,0};
    if (prow <= 510) {                    // plane row <- X row prow+1; 511 stays zero
      const float* px = X + (size_t)(prow + 1) * D_DIM + q * QK + gc * 8;
      float4 x0 = *(const float4*)px;
      float4 x1 = *(const float4*)(px + 4);
      const float* pw = W + 2 * (q * QK + gc * 8);
      float4 w0 = *(const float4*)(pw +  0);
      float4 w1 = *(const float4*)(pw +  4);
      float4 w2 = *(const float4*)(pw +  8);
      float4 w3 = *(const float4*)(pw + 12);
      vx.x = pkbf(x0.x, x0.y);            vx.y = pkbf(x0.z, x0.w);
      vx.z = pkbf(x1.x, x1.y);            vx.w = pkbf(x1.z, x1.w);
      v0.x = pkbf(x0.x*w0.x, x0.y*w0.z);  v0.y = pkbf(x0.z*w1.x, x0.w*w1.z);
      v0.z = pkbf(x1.x*w2.x, x1.y*w2.z);  v0.w = pkbf(x1.z*w3.x, x1.w*w3.z);
      v1.x = pkbf(x0.x*w0.y, x0.y*w0.w);  v1.y = pkbf(x0.z*w1.y, x0.w*w1.w);
      v1.z = pkbf(x1.x*w2.y, x1.y*w2.w);  v1.w = pkbf(x1.z*w3.y, x1.w*w3.w);
    }
    const int swzl = quad * 16 + ((lr + quad + 4 * s) & 15);   // bank-spread rotation
    *(uint4*)&sG[0][s][swzl][0] = vx;
    *(uint4*)&sG[1][s][swzl][0] = v0;
    *(uint4*)&sG[2][s][swzl][0] = v1;
  }
  __syncthreads();

  // ---- phase 2: 640 granules/plane, lane-linear NON-TEMPORAL stores ----
  for (int g = tid; g < 640; g += 256) {
    const int s = g >> 6, l = g & 63;
    const int quad = l >> 4, m = l & 15;
    const int swzl = quad * 16 + ((m + quad + 4 * s) & 15);
    const size_t go = ((size_t)((R * KSTEPS + q * 10 + s) * 64) + l) * 8;
    uint4n ux = *(const uint4n*)&sG[0][s][swzl][0];
    uint4n u0 = *(const uint4n*)&sG[1][s][swzl][0];
    uint4n u1 = *(const uint4n*)&sG[2][s][swzl][0];
    __builtin_nontemporal_store(ux, (uint4n*)(Xbf + go));
    __builtin_nontemporal_store(u0, (uint4n*)(A0  + go));
    __builtin_nontemporal_store(u1, (uint4n*)(A1  + go));
  }
}

// GEMM (byte-identical to R11/R12): upper triangle of 32x32 tile grid, 528 blocks,
// 16x16 tiles; 4 waves split K into quarters; lane-linear fragment loads; LDS
// reduce; off-diagonal blocks also store the transposed tile.
__global__ __launch_bounds__(256, 2) void pcmd_gemm(
    const unsigned short* __restrict__ Xbf,
    const unsigned short* __restrict__ A0,
    const unsigned short* __restrict__ A1,
    const float* __restrict__ b,
    float* __restrict__ out)            // [510][510][2]
{
  __shared__ float sR[4][2][16][17];

  const int t = (int)blockIdx.x;        // 0..527
  int bi = (int)((65.0 - sqrt(4225.0 - 8.0 * (double)t)) * 0.5);
  {
    int s0 = bi * 32 - (bi * (bi - 1)) / 2;
    if (t < s0) { --bi; }
    int s1 = (bi + 1) * 32 - ((bi + 1) * bi) / 2;
    if (t >= s1) { ++bi; }
  }
  const int start = bi * 32 - (bi * (bi - 1)) / 2;
  const int bj = bi + (t - start);

  const int tid  = threadIdx.x;
  const int lane = tid & 63;
  const int wv   = tid >> 6;

  const unsigned short* pa0 = A0  + ((size_t)(bi * KSTEPS + wv * 10) * 64 + lane) * 8;
  const unsigned short* pa1 = A1  + ((size_t)(bi * KSTEPS + wv * 10) * 64 + lane) * 8;
  const unsigned short* pb  = Xbf + ((size_t)(bj * KSTEPS + wv * 10) * 64 + lane) * 8;

  bf16x8 ra0[4], ra1[4], rb[4];
  #pragma unroll
  for (int s = 0; s < 4; ++s) {
    ra0[s] = *(const bf16x8*)(pa0 + s * 512);
    ra1[s] = *(const bf16x8*)(pa1 + s * 512);
    rb[s]  = *(const bf16x8*)(pb  + s * 512);
  }

  f32x4 acc0 = {0.f, 0.f, 0.f, 0.f};
  f32x4 acc1 = {0.f, 0.f, 0.f, 0.f};

  #pragma unroll
  for (int s = 0; s < 10; ++s) {
    const int cur = s & 3;
    bf16x8 a0 = ra0[cur], a1 = ra1[cur], bb = rb[cur];
    if (s + 4 < 10) {
      ra0[cur] = *(const bf16x8*)(pa0 + (s + 4) * 512);
      ra1[cur] = *(const bf16x8*)(pa1 + (s + 4) * 512);
      rb[cur]  = *(const bf16x8*)(pb  + (s + 4) * 512);
    }
    acc0 = __builtin_amdgcn_mfma_f32_16x16x32_bf16(a0, bb, acc0, 0, 0, 0);
    acc1 = __builtin_amdgcn_mfma_f32_16x16x32_bf16(a1, bb, acc1, 0, 0, 0);
  }

  const int m = lane & 15, quad = lane >> 4;
  #pragma unroll
  for (int r = 0; r < 4; ++r) {
    sR[wv][0][quad * 4 + r][m] = acc0[r];
    sR[wv][1][quad * 4 + r][m] = acc1[r];
  }
  __syncthreads();

  const float b0 = b[0], b1 = b[1];
  const int il = tid >> 4, jl = tid & 15;

  {
    const int oi = bi * 16 + il, oj = bj * 16 + jl;
    if (oi < ODIM && oj < ODIM) {
      float2 v;
      v.x = sR[0][0][il][jl] + sR[1][0][il][jl] + sR[2][0][il][jl] + sR[3][0][il][jl] + b0;
      v.y = sR[0][1][il][jl] + sR[1][1][il][jl] + sR[2][1][il][jl] + sR[3][1][il][jl] + b1;
      *(float2*)(out + ((size_t)oi * ODIM + oj) * 2) = v;
    }
  }
  if (bi != bj) {
    const int oi = bj * 16 + il, oj = bi * 16 + jl;
    if (oi < ODIM && oj < ODIM) {
      float2 v;
      v.x = sR[0][0][jl][il] + sR[1][0][jl][il] + sR[2][0][jl][il] + sR[3][0][jl][il] + b0;
      v.y = sR[0][1][jl][il] + sR[1][1][jl][il] + sR[2][1][jl][il] + sR[3][1][jl][il] + b1;
      *(float2*)(out + ((size_t)oi * ODIM + oj) * 2) = v;
    }
  }
}

extern "C" void kernel_launch(void* const* d_in, const int* in_sizes, int n_in,
                              void* d_out, int out_size, void* d_ws, size_t ws_size,
                              hipStream_t stream) {
  const float* X = (const float*)d_in[0];
  const float* W = (const float*)d_in[1];
  const float* b = (const float*)d_in[2];
  float* out = (float*)d_out;
  (void)in_sizes; (void)n_in; (void)out_size; (void)ws_size;

  const size_t PLANE = (size_t)512 * D_DIM;        // elements per bf16 plane
  unsigned short* Xbf = (unsigned short*)d_ws;
  unsigned short* A0  = Xbf + PLANE;
  unsigned short* A1  = A0 + PLANE;

  hipLaunchKernelGGL(pcmd_prep, dim3(128), dim3(256), 0, stream, X, W, Xbf, A0, A1);
  hipLaunchKernelGGL(pcmd_gemm, dim3(528), dim3(256), 0, stream, Xbf, A0, A1, b, out);
}